// Round 3
// baseline (436.297 us; speedup 1.0000x reference)
//
#include <hip/hip_runtime.h>

// CenterLoss R8 == R7 resubmitted verbatim (broker timeout x3; no counters yet).
// Rationale: two structural revisions (R6, R7) are already unverified; a third
// blind edit would make the first successful bench unattributable. Holding.
//
// feature [B=128, D=128, T=2048] f32, label [B*T] i32, centers [64,128] f32
// out: [1 + 64*128] f32 = (loss, difference)
//
// Theory (R0): R1-R5 were latency-bound at 1 block/CU (4 waves) with ~96
// barrier-synced phases; every throughput pipe <10% busy by arithmetic.
// R6/R7/R8: grid 1024 = (b:128, dh:2, th:4) -> 4 blocks/CU (16 waves/CU);
// counting-sort (classes padded to 4) -> each thread owns ONE single-class
// group of 4 slots -> gather 4 + 1 LDS float atomic per d-row. No partial[]
// round-trip, no owner phase: 2 barriers/iter x 16 iters. Block S_lds[64][65]
// flushed once via global f32 atomicAdd (4096/block); counts via global int
// atomics from dh==0 blocks, issued AFTER the hot loop (keeps vmcnt window
// clean). All waits/barriers wrapped in memory clobbers so the compiler
// cannot sink a global_load_lds issue past its counted vmcnt wait.

#define NT 2048
#define NC 64
#define TQ 512          // t per block
#define RB 520          // row stride floats: 512 data + zero slot @512 (16B mult)

// ws float offsets
#define OFF_S     0     // [64][128] f32 class sums   (global atomic, zeroed)
#define OFF_CNT   8192  // [64] int counts            (global atomic, zeroed)
#define OFF_SSP   8256  // [1024] per-block sumsq
#define OFF_CROSS 9280  // [32]  (written by k_red)
#define OFF_CC    9312  // [32]

// gfx9 s_waitcnt imm: vm[3:0]=bits3:0, exp=bits6:4, lgkm=bits11:8, vm[5:4]=bits15:14
#define CFENCE()     __asm__ volatile("" ::: "memory")
#define WAIT_VM0()   do { CFENCE(); __builtin_amdgcn_s_waitcnt(0x0F70); CFENCE(); } while (0)
#define WAIT_VM2()   do { CFENCE(); __builtin_amdgcn_s_waitcnt(0x0F72); CFENCE(); } while (0)
#define BAR()        do { CFENCE(); __builtin_amdgcn_s_barrier(); CFENCE(); } while (0)

__device__ __forceinline__ void dma16(const float* g, float* l) {
    __builtin_amdgcn_global_load_lds(
        (const __attribute__((address_space(1))) void*)g,
        (__attribute__((address_space(3))) void*)l, 16, 0, 0);
}

__global__ __launch_bounds__(256) void k_main(const float* __restrict__ feat,
                                              const int*  __restrict__ label,
                                              float* __restrict__ ws) {
    __shared__ float __attribute__((aligned(16))) rowbuf[2][4][RB]; // 16.6 KB
    __shared__ unsigned short __attribute__((aligned(16))) sorted[1024];
    __shared__ float S_lds[NC][65];                                  // 16.6 KB; stride 65 spreads classes over banks
    __shared__ float red[256];
    __shared__ int cnt[NC], pstart[NC], cursor[NC];
    __shared__ unsigned char gclass[256];
    // ~37.7 KB/block -> 4 blocks/CU (151 KB of 160)

    const int tid = threadIdx.x, bid = blockIdx.x;
    const int b = bid >> 3, dh = (bid >> 2) & 1, th = bid & 3;
    const int wave = tid >> 6, lane = tid & 63;

    // ---- init: all group slots -> zero-slot byte offset (float idx 512) ----
    for (int j = tid; j < 1024; j += 256) sorted[j] = (unsigned short)2048;
    if (tid < NC) { cnt[tid] = 0; cursor[tid] = 0; }
    gclass[tid] = 0;
    for (int j = tid; j < NC * 65; j += 256) ((float*)S_lds)[j] = 0.0f;
    if (tid < 64) rowbuf[tid >> 5][(tid >> 3) & 3][512 + (tid & 7)] = 0.0f;
    __syncthreads();

    // ---- histogram of this block's 512 labels ----
    const int* lp = label + b * NT + th * TQ + tid * 2;
    const int2 L = *(const int2*)lp;
    atomicAdd(&cnt[L.x], 1); atomicAdd(&cnt[L.y], 1);
    __syncthreads();

    // ---- prefix, classes padded to x4 (total <= 512 + 64*3 = 704 <= 1024) ----
    if (tid == 0) {
        int pt = 0;
        for (int c = 0; c < NC; ++c) {
            int pl = (cnt[c] + 3) & ~3;
            pstart[c] = pt; pt += pl;
        }
    }
    __syncthreads();

    // group -> class map; groups beyond padded total stay class 0 (gather zeros)
    if (tid < NC) {
        int g0 = pstart[tid] >> 2;
        int g1 = g0 + (((cnt[tid] + 3) & ~3) >> 2);
        for (int g = g0; g < g1; ++g) gclass[g] = (unsigned char)tid;
    }
    // scatter: sorted[pos] = within-row byte offset of t
    {
        int p = pstart[L.x] + atomicAdd(&cursor[L.x], 1);
        sorted[p] = (unsigned short)((tid * 2 + 0) * 4);
        p = pstart[L.y] + atomicAdd(&cursor[L.y], 1);
        sorted[p] = (unsigned short)((tid * 2 + 1) * 4);
    }
    __syncthreads();

    // ---- this thread's single-class group of 4 offsets + its class ----
    const uint2 pk = *(const uint2*)&sorted[tid * 4];
    const int off0 = pk.x & 0xFFFF, off1 = pk.x >> 16;
    const int off2 = pk.y & 0xFFFF, off3 = pk.y >> 16;
    const int myc = gclass[tid];

    // ---- main loop: 16 iters x 4 d-rows, double-buffered DMA staging ----
    // Per iter, the wave's 2 dma16 for iter i+1 are issued BEFORE waiting
    // vmcnt(2) (= iter-i's pair landed; i+1's pair stays in flight).
    const float* fbase = feat + ((size_t)b * 128 + dh * 64) * NT + th * TQ;
    float ss0 = 0.0f, ss1 = 0.0f, ss2 = 0.0f, ss3 = 0.0f;

    #pragma unroll
    for (int q = 0; q < 2; ++q) {            // issue rows 0..3 (iter 0)
        int m = wave + 4 * q, r = m >> 1, p = m & 1;
        dma16(fbase + (size_t)r * NT + p * 256 + lane * 4, &rowbuf[0][r][p * 256]);
    }

    for (int i = 0; i < 16; ++i) {
        const int buf = i & 1;
        if (i < 15) {
            const float* nb = fbase + (size_t)(4 * (i + 1)) * NT;
            #pragma unroll
            for (int q = 0; q < 2; ++q) {
                int m = wave + 4 * q, r = m >> 1, p = m & 1;
                dma16(nb + (size_t)r * NT + p * 256 + lane * 4, &rowbuf[buf ^ 1][r][p * 256]);
            }
            WAIT_VM2();
        } else {
            WAIT_VM0();
        }
        BAR();               // all waves' slices of rowbuf[buf] visible

        #pragma unroll
        for (int r = 0; r < 4; ++r) {
            const char* rb = (const char*)&rowbuf[buf][r][0];
            float v0 = *(const float*)(rb + off0);
            float v1 = *(const float*)(rb + off1);
            float v2 = *(const float*)(rb + off2);
            float v3 = *(const float*)(rb + off3);
            ss0 += v0 * v0; ss1 += v1 * v1;
            ss2 += v2 * v2; ss3 += v3 * v3;
            atomicAdd(&S_lds[myc][i * 4 + r], (v0 + v1) + (v2 + v3));
        }
        BAR();               // reads of rowbuf[buf] retired -> iter i+1 may overwrite
    }

    // ---- global counts (one label-slice per (b,th); gate on dh==0) ----
    if (dh == 0 && tid < NC) atomicAdd((int*)(ws + OFF_CNT) + tid, cnt[tid]);

    // ---- one-time flush: S_lds -> global atomic S ----
    __syncthreads();         // drains outstanding ds_add_f32
    {
        const int c = tid >> 2, j0 = (tid & 3) * 16;
        float* gS = ws + OFF_S + (size_t)c * 128 + dh * 64 + j0;
        #pragma unroll
        for (int j = 0; j < 16; ++j) atomicAdd(&gS[j], S_lds[c][j0 + j]);
    }

    // ---- block sumsq reduce ----
    red[tid] = (ss0 + ss1) + (ss2 + ss3);
    __syncthreads();
    for (int s = 128; s > 0; s >>= 1) {
        if (tid < s) red[tid] += red[tid + s];
        __syncthreads();
    }
    if (tid == 0) ws[OFF_SSP + bid] = red[0];
}

__global__ __launch_bounds__(256) void k_red(float* __restrict__ ws,
                                             const float* __restrict__ centers,
                                             float* __restrict__ out) {
    const int tid = threadIdx.x, bid = blockIdx.x;
    const int e = bid * 256 + tid, c = e >> 7;
    const float sum = ws[OFF_S + e];
    const float cn  = (float)((const int*)(ws + OFF_CNT))[c];
    const float ctr = centers[e];
    const float den = cn > 1.0f ? cn : 1.0f;
    out[1 + e] = (cn * ctr - sum) / den;

    __shared__ float r1[256], r2[256];
    r1[tid] = sum * ctr;          // cross term
    r2[tid] = cn * ctr * ctr;     // center-norm term
    __syncthreads();
    for (int k = 128; k > 0; k >>= 1) {
        if (tid < k) { r1[tid] += r1[tid + k]; r2[tid] += r2[tid + k]; }
        __syncthreads();
    }
    if (tid == 0) { ws[OFF_CROSS + bid] = r1[0]; ws[OFF_CC + bid] = r2[0]; }
}

__global__ __launch_bounds__(256) void k_epi(const float* __restrict__ ws,
                                             float* __restrict__ out) {
    const int tid = threadIdx.x;
    __shared__ float r[256];
    float s = ws[OFF_SSP + tid] + ws[OFF_SSP + tid + 256]
            + ws[OFF_SSP + tid + 512] + ws[OFF_SSP + tid + 768];
    if (tid < 32) s += ws[OFF_CC + tid] - 2.0f * ws[OFF_CROSS + tid];
    r[tid] = s;
    __syncthreads();
    for (int k = 128; k > 0; k >>= 1) {
        if (tid < k) r[tid] += r[tid + k];
        __syncthreads();
    }
    if (tid == 0) out[0] = r[0] * (1.0f / 33554432.0f);  // / (N*D), N = B*T
}

extern "C" void kernel_launch(void* const* d_in, const int* in_sizes, int n_in,
                              void* d_out, int out_size, void* d_ws, size_t ws_size,
                              hipStream_t stream) {
    const float* feat    = (const float*)d_in[0];
    const int*   label   = (const int*)d_in[1];
    const float* centers = (const float*)d_in[2];
    float* out = (float*)d_out;
    float* ws  = (float*)d_ws;

    // zero the atomic accumulators (S + CNT) each launch; capture-safe stream op
    hipMemsetAsync(ws, 0, (8192 + 64) * sizeof(float), stream);
    hipLaunchKernelGGL(k_main, dim3(1024), dim3(256), 0, stream, feat, label, ws);
    hipLaunchKernelGGL(k_red,  dim3(32),   dim3(256), 0, stream, ws, centers, out);
    hipLaunchKernelGGL(k_epi,  dim3(1),    dim3(256), 0, stream, ws, out);
}

// Round 4
// 279.758 us; speedup vs baseline: 1.5596x; 1.5596x over previous
//
#include <hip/hip_runtime.h>

// CenterLoss R9: kill the global-atomic flush wall.
// R8 counters: WRITE_SIZE = 131232 KB = 4.19M atomics x 32B EA writes; FETCH
// 67MB = 4.19M x 16B atomic fetches; dur 287us = 202MB / 705GB/s. The flush
// (1024 blocks x 4096 global f32 atomicAdd, 512 writers/address) WAS the
// kernel. Fix: non-atomic per-block partial stores (16.8 MB) + k_red_p sums
// 512 partials per output element. Atomics: 4.19M -> 8K (counts only).
// ws_size guard: if workspace < 16.8 MB, fall back to the R8 atomic path.

#define NT 2048
#define NC 64
#define TQ 512          // t per block
#define RB 520          // row stride floats: 512 data + zero slot @512 (16B mult)

// ws float offsets
#define OFF_S     0        // [8192] fallback atomic S (zeroed)
#define OFF_CNT   8192     // [64] int counts (global atomic, zeroed)
#define OFF_SSP   8256     // [1024] per-block sumsq
#define OFF_CROSS 9280     // [256]
#define OFF_CC    9536     // [256]
#define OFF_P     9792     // [1024][4096] per-block partials (main path)
#define WS_NEED_BYTES ((size_t)(OFF_P + 1024 * 4096) * 4)

// gfx9 s_waitcnt imm: vm[3:0]=bits3:0, exp=bits6:4, lgkm=bits11:8, vm[5:4]=bits15:14
#define CFENCE()     __asm__ volatile("" ::: "memory")
#define WAIT_VM0()   do { CFENCE(); __builtin_amdgcn_s_waitcnt(0x0F70); CFENCE(); } while (0)
#define WAIT_VM2()   do { CFENCE(); __builtin_amdgcn_s_waitcnt(0x0F72); CFENCE(); } while (0)
#define BAR()        do { CFENCE(); __builtin_amdgcn_s_barrier(); CFENCE(); } while (0)

__device__ __forceinline__ void dma16(const float* g, float* l) {
    __builtin_amdgcn_global_load_lds(
        (const __attribute__((address_space(1))) void*)g,
        (__attribute__((address_space(3))) void*)l, 16, 0, 0);
}

template <bool PARTIAL>
__global__ __launch_bounds__(256) void k_main(const float* __restrict__ feat,
                                              const int*  __restrict__ label,
                                              float* __restrict__ ws) {
    __shared__ float __attribute__((aligned(16))) rowbuf[2][4][RB];
    __shared__ unsigned short __attribute__((aligned(16))) sorted[1024];
    __shared__ float S_lds[NC][65];
    __shared__ float red[256];
    __shared__ int cnt[NC], pstart[NC], cursor[NC];
    __shared__ unsigned char gclass[256];

    const int tid = threadIdx.x, bid = blockIdx.x;
    const int b = bid >> 3, dh = (bid >> 2) & 1, th = bid & 3;
    const int wave = tid >> 6, lane = tid & 63;

    // ---- init: all group slots -> zero-slot byte offset (float idx 512) ----
    for (int j = tid; j < 1024; j += 256) sorted[j] = (unsigned short)2048;
    if (tid < NC) { cnt[tid] = 0; cursor[tid] = 0; }
    gclass[tid] = 0;
    for (int j = tid; j < NC * 65; j += 256) ((float*)S_lds)[j] = 0.0f;
    if (tid < 64) rowbuf[tid >> 5][(tid >> 3) & 3][512 + (tid & 7)] = 0.0f;
    __syncthreads();

    // ---- histogram of this block's 512 labels ----
    const int* lp = label + b * NT + th * TQ + tid * 2;
    const int2 L = *(const int2*)lp;
    atomicAdd(&cnt[L.x], 1); atomicAdd(&cnt[L.y], 1);
    __syncthreads();

    // ---- prefix, classes padded to x4 (total <= 512 + 64*3 = 704 <= 1024) ----
    if (tid == 0) {
        int pt = 0;
        for (int c = 0; c < NC; ++c) {
            int pl = (cnt[c] + 3) & ~3;
            pstart[c] = pt; pt += pl;
        }
    }
    __syncthreads();

    // group -> class map; groups beyond padded total stay class 0 (gather zeros)
    if (tid < NC) {
        int g0 = pstart[tid] >> 2;
        int g1 = g0 + (((cnt[tid] + 3) & ~3) >> 2);
        for (int g = g0; g < g1; ++g) gclass[g] = (unsigned char)tid;
    }
    // scatter: sorted[pos] = within-row byte offset of t
    {
        int p = pstart[L.x] + atomicAdd(&cursor[L.x], 1);
        sorted[p] = (unsigned short)((tid * 2 + 0) * 4);
        p = pstart[L.y] + atomicAdd(&cursor[L.y], 1);
        sorted[p] = (unsigned short)((tid * 2 + 1) * 4);
    }
    __syncthreads();

    // ---- this thread's single-class group of 4 offsets + its class ----
    const uint2 pk = *(const uint2*)&sorted[tid * 4];
    const int off0 = pk.x & 0xFFFF, off1 = pk.x >> 16;
    const int off2 = pk.y & 0xFFFF, off3 = pk.y >> 16;
    const int myc = gclass[tid];

    // ---- main loop: 16 iters x 4 d-rows, double-buffered DMA staging ----
    const float* fbase = feat + ((size_t)b * 128 + dh * 64) * NT + th * TQ;
    float ss0 = 0.0f, ss1 = 0.0f, ss2 = 0.0f, ss3 = 0.0f;

    #pragma unroll
    for (int q = 0; q < 2; ++q) {            // issue rows 0..3 (iter 0)
        int m = wave + 4 * q, r = m >> 1, p = m & 1;
        dma16(fbase + (size_t)r * NT + p * 256 + lane * 4, &rowbuf[0][r][p * 256]);
    }

    for (int i = 0; i < 16; ++i) {
        const int buf = i & 1;
        if (i < 15) {
            const float* nb = fbase + (size_t)(4 * (i + 1)) * NT;
            #pragma unroll
            for (int q = 0; q < 2; ++q) {
                int m = wave + 4 * q, r = m >> 1, p = m & 1;
                dma16(nb + (size_t)r * NT + p * 256 + lane * 4, &rowbuf[buf ^ 1][r][p * 256]);
            }
            WAIT_VM2();      // iter-i's pair landed; iter-(i+1)'s stays in flight
        } else {
            WAIT_VM0();
        }
        BAR();               // all waves' slices of rowbuf[buf] visible

        #pragma unroll
        for (int r = 0; r < 4; ++r) {
            const char* rb = (const char*)&rowbuf[buf][r][0];
            float v0 = *(const float*)(rb + off0);
            float v1 = *(const float*)(rb + off1);
            float v2 = *(const float*)(rb + off2);
            float v3 = *(const float*)(rb + off3);
            ss0 += v0 * v0; ss1 += v1 * v1;
            ss2 += v2 * v2; ss3 += v3 * v3;
            atomicAdd(&S_lds[myc][i * 4 + r], (v0 + v1) + (v2 + v3));
        }
        BAR();               // reads retired -> iter i+1 may overwrite rowbuf[buf]
    }

    // ---- global counts (one label-slice per (b,th); gate on dh==0) ----
    if (dh == 0 && tid < NC) atomicAdd((int*)(ws + OFF_CNT) + tid, cnt[tid]);

    __syncthreads();         // drains outstanding ds_add_f32
    if (PARTIAL) {
        // non-atomic flush: block-contiguous 4096 floats, fully coalesced
        const int c = tid >> 2, j0 = (tid & 3) * 16;
        float* gP = ws + OFF_P + (size_t)bid * 4096 + c * 64 + j0;
        float4 v0, v1, v2, v3;
        v0.x = S_lds[c][j0 +  0]; v0.y = S_lds[c][j0 +  1];
        v0.z = S_lds[c][j0 +  2]; v0.w = S_lds[c][j0 +  3];
        v1.x = S_lds[c][j0 +  4]; v1.y = S_lds[c][j0 +  5];
        v1.z = S_lds[c][j0 +  6]; v1.w = S_lds[c][j0 +  7];
        v2.x = S_lds[c][j0 +  8]; v2.y = S_lds[c][j0 +  9];
        v2.z = S_lds[c][j0 + 10]; v2.w = S_lds[c][j0 + 11];
        v3.x = S_lds[c][j0 + 12]; v3.y = S_lds[c][j0 + 13];
        v3.z = S_lds[c][j0 + 14]; v3.w = S_lds[c][j0 + 15];
        *(float4*)gP       = v0;
        *(float4*)(gP + 4) = v1;
        *(float4*)(gP + 8) = v2;
        *(float4*)(gP + 12) = v3;
    } else {
        // fallback: global atomic flush (R8 path; known-correct, slow)
        const int c = tid >> 2, j0 = (tid & 3) * 16;
        float* gS = ws + OFF_S + (size_t)c * 128 + dh * 64 + j0;
        #pragma unroll
        for (int j = 0; j < 16; ++j) atomicAdd(&gS[j], S_lds[c][j0 + j]);
    }

    // ---- block sumsq reduce ----
    red[tid] = (ss0 + ss1) + (ss2 + ss3);
    __syncthreads();
    for (int s = 128; s > 0; s >>= 1) {
        if (tid < s) red[tid] += red[tid + s];
        __syncthreads();
    }
    if (tid == 0) ws[OFF_SSP + bid] = red[0];
}

// main-path reduction: each block owns 32 (c,d) elements; 8 slices sum 64
// partial-blocks each (512 contributors per element = 128 b x 4 th).
__global__ __launch_bounds__(256) void k_red_p(float* __restrict__ ws,
                                               const float* __restrict__ centers,
                                               float* __restrict__ out) {
    const int tid = threadIdx.x, bid = blockIdx.x;
    const int j = tid & 31, s = tid >> 5;
    const int e = bid * 32 + j;
    const int c = e >> 7, d = e & 127, dhh = d >> 6, dl = d & 63;

    const float* base = ws + OFF_P + ((size_t)dhh * 4) * 4096 + c * 64 + dl;
    float sum = 0.0f;
    for (int b = s * 16; b < s * 16 + 16; ++b) {
        const float* pb = base + (size_t)b * 8 * 4096;
        sum += (pb[0] + pb[4096]) + (pb[2 * 4096] + pb[3 * 4096]);
    }

    __shared__ float red[256];
    red[tid] = sum;
    __syncthreads();
    if (tid < 128) red[tid] += red[tid + 128];
    __syncthreads();
    if (tid < 64)  red[tid] += red[tid + 64];
    __syncthreads();

    if (tid < 32) {
        const float tot = red[tid] + red[tid + 32];
        const float cn  = (float)((const int*)(ws + OFF_CNT))[c];
        const float ctr = centers[e];
        const float den = cn > 1.0f ? cn : 1.0f;
        out[1 + e] = (cn * ctr - tot) / den;

        float r1 = tot * ctr;          // cross term
        float r2 = cn * ctr * ctr;     // center-norm term
        for (int o = 16; o > 0; o >>= 1) {
            r1 += __shfl_down(r1, o, 32);
            r2 += __shfl_down(r2, o, 32);
        }
        if (tid == 0) { ws[OFF_CROSS + bid] = r1; ws[OFF_CC + bid] = r2; }
    }
}

// fallback reduction over the atomic S (R8 path)
__global__ __launch_bounds__(256) void k_red_a(float* __restrict__ ws,
                                               const float* __restrict__ centers,
                                               float* __restrict__ out) {
    const int tid = threadIdx.x, bid = blockIdx.x;
    const int e = bid * 256 + tid, c = e >> 7;
    const float sum = ws[OFF_S + e];
    const float cn  = (float)((const int*)(ws + OFF_CNT))[c];
    const float ctr = centers[e];
    const float den = cn > 1.0f ? cn : 1.0f;
    out[1 + e] = (cn * ctr - sum) / den;

    __shared__ float r1[256], r2[256];
    r1[tid] = sum * ctr;
    r2[tid] = cn * ctr * ctr;
    __syncthreads();
    for (int k = 128; k > 0; k >>= 1) {
        if (tid < k) { r1[tid] += r1[tid + k]; r2[tid] += r2[tid + k]; }
        __syncthreads();
    }
    if (tid == 0) { ws[OFF_CROSS + bid] = r1[0]; ws[OFF_CC + bid] = r2[0]; }
}

__global__ __launch_bounds__(256) void k_epi(const float* __restrict__ ws,
                                             float* __restrict__ out,
                                             int ncross) {
    const int tid = threadIdx.x;
    __shared__ float r[256];
    float s = ws[OFF_SSP + tid] + ws[OFF_SSP + tid + 256]
            + ws[OFF_SSP + tid + 512] + ws[OFF_SSP + tid + 768];
    if (tid < ncross) s += ws[OFF_CC + tid] - 2.0f * ws[OFF_CROSS + tid];
    r[tid] = s;
    __syncthreads();
    for (int k = 128; k > 0; k >>= 1) {
        if (tid < k) r[tid] += r[tid + k];
        __syncthreads();
    }
    if (tid == 0) out[0] = r[0] * (1.0f / 33554432.0f);  // / (N*D), N = B*T
}

extern "C" void kernel_launch(void* const* d_in, const int* in_sizes, int n_in,
                              void* d_out, int out_size, void* d_ws, size_t ws_size,
                              hipStream_t stream) {
    const float* feat    = (const float*)d_in[0];
    const int*   label   = (const int*)d_in[1];
    const float* centers = (const float*)d_in[2];
    float* out = (float*)d_out;
    float* ws  = (float*)d_ws;

    // zero atomic accumulators (S fallback + CNT); capture-safe stream op
    hipMemsetAsync(ws, 0, 8256 * sizeof(float), stream);

    if (ws_size >= WS_NEED_BYTES) {
        hipLaunchKernelGGL(k_main<true>,  dim3(1024), dim3(256), 0, stream, feat, label, ws);
        hipLaunchKernelGGL(k_red_p, dim3(256), dim3(256), 0, stream, ws, centers, out);
        hipLaunchKernelGGL(k_epi,   dim3(1),   dim3(256), 0, stream, ws, out, 256);
    } else {
        hipLaunchKernelGGL(k_main<false>, dim3(1024), dim3(256), 0, stream, feat, label, ws);
        hipLaunchKernelGGL(k_red_a, dim3(32),  dim3(256), 0, stream, ws, centers, out);
        hipLaunchKernelGGL(k_epi,   dim3(1),   dim3(256), 0, stream, ws, out, 32);
    }
}

// Round 10
// 273.264 us; speedup vs baseline: 1.5966x; 1.0238x over previous
//
#include <hip/hip_runtime.h>

// CenterLoss R15 == R10..R14 resubmitted verbatim (6th broker timeout; the
// barrier-free structure has never executed). Holding for clean attribution.
//
// NEW desk analysis this round - the ~148us total-minus-k_main gap (constant
// across R8/R9) now has 3 pre-committed hypotheses, discriminated by THIS
// kernel's next successful bench:
//  H-fixed:   harness/graph overhead -> total ~ k_main+148 (~185us). Next:
//             fuse k_epi into k_red_p (arrival counter), drop memset (revert
//             CNT to non-atomic per-block slots as in the R5 ancestor).
//  H-coupled: overhead scales w/ k_main grid or rocprof artifact -> total
//             ~ k_main+35 (~70-80us). Next: push k_main toward 21us floor.
//  H-red:     k_red_p secretly latency-bound (~110us for 16.8MB). Next:
//             512+ blocks + deeper unroll.
// Old-session check that killed "pure H-fixed": R5-era total 212us with
// k_main ~180 implies old gap ~32us, so 148 is at least partly ours.
//
// R9 counters (last real data): k_main 131.5us, 647 GB/s (8%), VALUBusy 3.3%
// -> latency-bound; 8.2us/iter for 32KB DMA: 2-barrier lockstep drains the
// memory system every iteration. This kernel: wave w owns rows w+4i, private
// triple-buffered slot, depth-3 prefetch, counted vmcnt(4), ZERO barriers in
// the hot loop. Lane-level sort groups (lane owns {lane,64+lane,128+lane})
// -> 12 gathers + 3 LDS atomics per row; S_lds columns disjoint per wave.
// Flush + k_red_p unchanged from harness-verified R9.

#define NT 2048
#define NC 64
#define TQ 512          // t per block
#define RB 520          // row stride floats: 512 data + zero slot @512 (16B mult)

// ws float offsets (identical to R9 - proven to fit)
#define OFF_S     0        // [8192] fallback atomic S (zeroed)
#define OFF_CNT   8192     // [64] int counts (global atomic, zeroed)
#define OFF_SSP   8256     // [1024] per-block sumsq
#define OFF_CROSS 9280     // [256]
#define OFF_CC    9536     // [256]
#define OFF_P     9792     // [1024][4096] per-block partials (main path)
#define WS_NEED_BYTES ((size_t)(OFF_P + 1024 * 4096) * 4)

// gfx9 s_waitcnt imm: vm[3:0]=bits3:0, exp=bits6:4, lgkm=bits11:8, vm[5:4]=bits15:14
#define CFENCE()     __asm__ volatile("" ::: "memory")
#define WAIT_VM0()   do { CFENCE(); __builtin_amdgcn_s_waitcnt(0x0F70); CFENCE(); } while (0)
#define WAIT_VM2()   do { CFENCE(); __builtin_amdgcn_s_waitcnt(0x0F72); CFENCE(); } while (0)
#define WAIT_VM4()   do { CFENCE(); __builtin_amdgcn_s_waitcnt(0x0F74); CFENCE(); } while (0)

__device__ __forceinline__ void dma16(const float* g, float* l) {
    __builtin_amdgcn_global_load_lds(
        (const __attribute__((address_space(1))) void*)g,
        (__attribute__((address_space(3))) void*)l, 16, 0, 0);
}

template <bool PARTIAL>
__global__ __launch_bounds__(256) void k_main(const float* __restrict__ feat,
                                              const int*  __restrict__ label,
                                              float* __restrict__ ws) {
    __shared__ float __attribute__((aligned(16))) rowbuf[4][3][RB]; // wave-private triple buffer, 24.9 KB
    __shared__ unsigned short __attribute__((aligned(16))) sorted[1024];
    __shared__ float S_lds[NC][65];                                  // 16.6 KB; odd stride spreads class banks
    __shared__ float red[256];
    __shared__ int cnt[NC], pstart[NC], cursor[NC];
    __shared__ unsigned char gclass[192];
    // ~46.6 KB/block -> 3 blocks/CU (12 waves/CU)

    const int tid = threadIdx.x, bid = blockIdx.x;
    const int b = bid >> 3, dh = (bid >> 2) & 1, th = bid & 3;
    const int w = tid >> 6, lane = tid & 63;

    // ---- init: all group slots -> zero-slot byte offset (float idx 512) ----
    for (int j = tid; j < 1024; j += 256) sorted[j] = (unsigned short)2048;
    if (tid < NC) { cnt[tid] = 0; cursor[tid] = 0; }
    if (tid < 192) gclass[tid] = 0;
    for (int j = tid; j < NC * 65; j += 256) ((float*)S_lds)[j] = 0.0f;
    if (tid < 96) {                          // zero slots of all 12 row buffers
        const int ww = tid / 24, rem = tid % 24;
        rowbuf[ww][rem >> 3][512 + (rem & 7)] = 0.0f;
    }
    __syncthreads();

    // ---- histogram of this block's 512 labels ----
    const int* lp = label + b * NT + th * TQ + tid * 2;
    const int2 L = *(const int2*)lp;
    atomicAdd(&cnt[L.x], 1); atomicAdd(&cnt[L.y], 1);
    __syncthreads();

    // ---- prefix, classes padded to x4 (total <= 704 -> <=176 groups) ----
    if (tid == 0) {
        int pt = 0;
        for (int c = 0; c < NC; ++c) {
            int pl = (cnt[c] + 3) & ~3;
            pstart[c] = pt; pt += pl;
        }
    }
    __syncthreads();

    // group -> class map; groups beyond padded total stay class 0 (gather zeros)
    if (tid < NC) {
        int g0 = pstart[tid] >> 2;
        int g1 = g0 + (((cnt[tid] + 3) & ~3) >> 2);
        for (int g = g0; g < g1; ++g) gclass[g] = (unsigned char)tid;
    }
    // scatter: sorted[pos] = within-row byte offset of t
    {
        int p = pstart[L.x] + atomicAdd(&cursor[L.x], 1);
        sorted[p] = (unsigned short)((tid * 2 + 0) * 4);
        p = pstart[L.y] + atomicAdd(&cursor[L.y], 1);
        sorted[p] = (unsigned short)((tid * 2 + 1) * 4);
    }
    __syncthreads();

    // ---- lane-level groups: lane owns groups {lane, 64+lane, 128+lane} ----
    int offs[3][4]; int cls[3];
    #pragma unroll
    for (int g3 = 0; g3 < 3; ++g3) {
        const int g = lane + 64 * g3;
        const uint2 pk = *(const uint2*)&sorted[g * 4];
        offs[g3][0] = pk.x & 0xFFFF; offs[g3][1] = pk.x >> 16;
        offs[g3][2] = pk.y & 0xFFFF; offs[g3][3] = pk.y >> 16;
        cls[g3] = gclass[g];
    }

    // ---- barrier-free hot loop: wave w rows w+4i, depth-3 prefetch ----
    const float* fbase = feat + ((size_t)b * 128 + dh * 64) * NT + th * TQ;
    float ssA = 0.0f, ssB = 0.0f;

#define ISSUE(i_, s_) do {                                            \
        const float* rp_ = fbase + (size_t)(w + 4 * (i_)) * NT;       \
        dma16(rp_ + lane * 4,       &rowbuf[w][s_][0]);               \
        dma16(rp_ + 256 + lane * 4, &rowbuf[w][s_][256]);             \
    } while (0)

    ISSUE(0, 0); ISSUE(1, 1);               // rows w, w+4 in flight
    int slot = 0;
    for (int i = 0; i < 16; ++i) {
        CFENCE();                            // order prior slot reads vs new DMA issue
        if (i < 14) {
            int s2 = slot + 2; if (s2 >= 3) s2 -= 3;
            ISSUE(i + 2, s2);                // overwrites slot gathered at i-1 (reads retired)
            WAIT_VM4();                      // row i landed; rows i+1, i+2 in flight
        } else if (i == 14) {
            WAIT_VM2();
        } else {
            WAIT_VM0();
        }

        const char* rb = (const char*)&rowbuf[w][slot][0];
        const int dslot = w + 4 * i;         // d-index this wave accumulates (disjoint per wave)
        #pragma unroll
        for (int g3 = 0; g3 < 3; ++g3) {
            float v0 = *(const float*)(rb + offs[g3][0]);
            float v1 = *(const float*)(rb + offs[g3][1]);
            float v2 = *(const float*)(rb + offs[g3][2]);
            float v3 = *(const float*)(rb + offs[g3][3]);
            ssA += v0 * v0 + v1 * v1;
            ssB += v2 * v2 + v3 * v3;
            atomicAdd(&S_lds[cls[g3]][dslot], (v0 + v1) + (v2 + v3));
        }
        ++slot; if (slot == 3) slot = 0;
    }
#undef ISSUE

    // ---- global counts (one label-slice per (b,th); gate on dh==0) ----
    if (dh == 0 && tid < NC) atomicAdd((int*)(ws + OFF_CNT) + tid, cnt[tid]);

    __syncthreads();         // drains outstanding ds_add_f32; S_lds complete
    if (PARTIAL) {
        // non-atomic flush: block-contiguous 4096 floats, fully coalesced
        const int c = tid >> 2, j0 = (tid & 3) * 16;
        float* gP = ws + OFF_P + (size_t)bid * 4096 + c * 64 + j0;
        float4 v0, v1, v2, v3;
        v0.x = S_lds[c][j0 +  0]; v0.y = S_lds[c][j0 +  1];
        v0.z = S_lds[c][j0 +  2]; v0.w = S_lds[c][j0 +  3];
        v1.x = S_lds[c][j0 +  4]; v1.y = S_lds[c][j0 +  5];
        v1.z = S_lds[c][j0 +  6]; v1.w = S_lds[c][j0 +  7];
        v2.x = S_lds[c][j0 +  8]; v2.y = S_lds[c][j0 +  9];
        v2.z = S_lds[c][j0 + 10]; v2.w = S_lds[c][j0 + 11];
        v3.x = S_lds[c][j0 + 12]; v3.y = S_lds[c][j0 + 13];
        v3.z = S_lds[c][j0 + 14]; v3.w = S_lds[c][j0 + 15];
        *(float4*)gP        = v0;
        *(float4*)(gP + 4)  = v1;
        *(float4*)(gP + 8)  = v2;
        *(float4*)(gP + 12) = v3;
    } else {
        // fallback: global atomic flush (R8 path; correct, slow)
        const int c = tid >> 2, j0 = (tid & 3) * 16;
        float* gS = ws + OFF_S + (size_t)c * 128 + dh * 64 + j0;
        #pragma unroll
        for (int j = 0; j < 16; ++j) atomicAdd(&gS[j], S_lds[c][j0 + j]);
    }

    // ---- block sumsq reduce ----
    red[tid] = ssA + ssB;
    __syncthreads();
    for (int s = 128; s > 0; s >>= 1) {
        if (tid < s) red[tid] += red[tid + s];
        __syncthreads();
    }
    if (tid == 0) ws[OFF_SSP + bid] = red[0];
}

// main-path reduction: each block owns 32 (c,d) elements; 8 slices sum 64
// partial-blocks each (512 contributors per element = 128 b x 4 th).
__global__ __launch_bounds__(256) void k_red_p(float* __restrict__ ws,
                                               const float* __restrict__ centers,
                                               float* __restrict__ out) {
    const int tid = threadIdx.x, bid = blockIdx.x;
    const int j = tid & 31, s = tid >> 5;
    const int e = bid * 32 + j;
    const int c = e >> 7, d = e & 127, dhh = d >> 6, dl = d & 63;

    const float* base = ws + OFF_P + ((size_t)dhh * 4) * 4096 + c * 64 + dl;
    float sum = 0.0f;
    for (int b = s * 16; b < s * 16 + 16; ++b) {
        const float* pb = base + (size_t)b * 8 * 4096;
        sum += (pb[0] + pb[4096]) + (pb[2 * 4096] + pb[3 * 4096]);
    }

    __shared__ float red[256];
    red[tid] = sum;
    __syncthreads();
    if (tid < 128) red[tid] += red[tid + 128];
    __syncthreads();
    if (tid < 64)  red[tid] += red[tid + 64];
    __syncthreads();

    if (tid < 32) {
        const float tot = red[tid] + red[tid + 32];
        const float cn  = (float)((const int*)(ws + OFF_CNT))[c];
        const float ctr = centers[e];
        const float den = cn > 1.0f ? cn : 1.0f;
        out[1 + e] = (cn * ctr - tot) / den;

        float r1 = tot * ctr;          // cross term
        float r2 = cn * ctr * ctr;     // center-norm term
        for (int o = 16; o > 0; o >>= 1) {
            r1 += __shfl_down(r1, o, 32);
            r2 += __shfl_down(r2, o, 32);
        }
        if (tid == 0) { ws[OFF_CROSS + bid] = r1; ws[OFF_CC + bid] = r2; }
    }
}

// fallback reduction over the atomic S (R8 path)
__global__ __launch_bounds__(256) void k_red_a(float* __restrict__ ws,
                                               const float* __restrict__ centers,
                                               float* __restrict__ out) {
    const int tid = threadIdx.x, bid = blockIdx.x;
    const int e = bid * 256 + tid, c = e >> 7;
    const float sum = ws[OFF_S + e];
    const float cn  = (float)((const int*)(ws + OFF_CNT))[c];
    const float ctr = centers[e];
    const float den = cn > 1.0f ? cn : 1.0f;
    out[1 + e] = (cn * ctr - sum) / den;

    __shared__ float r1[256], r2[256];
    r1[tid] = sum * ctr;
    r2[tid] = cn * ctr * ctr;
    __syncthreads();
    for (int k = 128; k > 0; k >>= 1) {
        if (tid < k) { r1[tid] += r1[tid + k]; r2[tid] += r2[tid + k]; }
        __syncthreads();
    }
    if (tid == 0) { ws[OFF_CROSS + bid] = r1[0]; ws[OFF_CC + bid] = r2[0]; }
}

__global__ __launch_bounds__(256) void k_epi(const float* __restrict__ ws,
                                             float* __restrict__ out,
                                             int ncross) {
    const int tid = threadIdx.x;
    __shared__ float r[256];
    float s = ws[OFF_SSP + tid] + ws[OFF_SSP + tid + 256]
            + ws[OFF_SSP + tid + 512] + ws[OFF_SSP + tid + 768];
    if (tid < ncross) s += ws[OFF_CC + tid] - 2.0f * ws[OFF_CROSS + tid];
    r[tid] = s;
    __syncthreads();
    for (int k = 128; k > 0; k >>= 1) {
        if (tid < k) r[tid] += r[tid + k];
        __syncthreads();
    }
    if (tid == 0) out[0] = r[0] * (1.0f / 33554432.0f);  // / (N*D), N = B*T
}

extern "C" void kernel_launch(void* const* d_in, const int* in_sizes, int n_in,
                              void* d_out, int out_size, void* d_ws, size_t ws_size,
                              hipStream_t stream) {
    const float* feat    = (const float*)d_in[0];
    const int*   label   = (const int*)d_in[1];
    const float* centers = (const float*)d_in[2];
    float* out = (float*)d_out;
    float* ws  = (float*)d_ws;

    // zero atomic accumulators (S fallback + CNT); capture-safe stream op
    hipMemsetAsync(ws, 0, 8256 * sizeof(float), stream);

    if (ws_size >= WS_NEED_BYTES) {
        hipLaunchKernelGGL(k_main<true>,  dim3(1024), dim3(256), 0, stream, feat, label, ws);
        hipLaunchKernelGGL(k_red_p, dim3(256), dim3(256), 0, stream, ws, centers, out);
        hipLaunchKernelGGL(k_epi,   dim3(1),   dim3(256), 0, stream, ws, out, 256);
    } else {
        hipLaunchKernelGGL(k_main<false>, dim3(1024), dim3(256), 0, stream, feat, label, ws);
        hipLaunchKernelGGL(k_red_a, dim3(32),  dim3(256), 0, stream, ws, centers, out);
        hipLaunchKernelGGL(k_epi,   dim3(1),   dim3(256), 0, stream, ws, out, 32);
    }
}

// Round 11
// 248.384 us; speedup vs baseline: 1.7565x; 1.1002x over previous
//
#include <hip/hip_runtime.h>

// CenterLoss R16: replace global_load_lds with reg-staged loads.
// Post-mortem R10: barrier-free restructure gave only 131.5->124us. Effective
// BW pinned at ~680 GB/s across THREE different structures (R8 atomic flush
// 705, R9 lockstep 647, R10 free-run 686) -> the wall is the staging
// mechanism, not scheduling. Hypothesis: global_load_lds return path
// serializes per CU (~1KB/latency ~ 1.1 GB/s/CU ~ observed 2.7 incl. cache
// hits); m97 GEMM only sustained high BW with it from L2-resident tiles.
// Fix: global_load_dwordx4 -> VGPR (6.3 TB/s proven path, m13) -> ds_write
// -> identical gather. 2-deep reg pipeline, 2 LDS slots/wave, LDS 37.9KB ->
// 4 blocks/CU. Sort/gather/S_lds/flush/k_red_p/k_epi all unchanged.

#define NT 2048
#define NC 64
#define TQ 512          // t per block
#define RB 520          // row slot floats: 512 data + zero slot @512 (16B mult)

// ws float offsets (identical to R9/R10 - proven)
#define OFF_S     0        // [8192] fallback atomic S (zeroed)
#define OFF_CNT   8192     // [64] int counts (global atomic, zeroed)
#define OFF_SSP   8256     // [1024] per-block sumsq
#define OFF_CROSS 9280     // [256]
#define OFF_CC    9536     // [256]
#define OFF_P     9792     // [1024][4096] per-block partials (main path)
#define WS_NEED_BYTES ((size_t)(OFF_P + 1024 * 4096) * 4)

template <bool PARTIAL>
__global__ __launch_bounds__(256) void k_main(const float* __restrict__ feat,
                                              const int*  __restrict__ label,
                                              float* __restrict__ ws) {
    __shared__ float __attribute__((aligned(16))) rowbuf[4][2][RB]; // wave-private double slot, 16.6 KB
    __shared__ unsigned short __attribute__((aligned(16))) sorted[1024];
    __shared__ float S_lds[NC][65];                                  // 16.6 KB; odd stride spreads class banks
    __shared__ float red[256];
    __shared__ int cnt[NC], pstart[NC], cursor[NC];
    __shared__ unsigned char gclass[192];
    // ~37.9 KB/block -> 4 blocks/CU (16 waves/CU)

    const int tid = threadIdx.x, bid = blockIdx.x;
    const int b = bid >> 3, dh = (bid >> 2) & 1, th = bid & 3;
    const int w = tid >> 6, lane = tid & 63;

    // ---- init ----
    for (int j = tid; j < 1024; j += 256) sorted[j] = (unsigned short)2048;
    if (tid < NC) { cnt[tid] = 0; cursor[tid] = 0; }
    if (tid < 192) gclass[tid] = 0;
    for (int j = tid; j < NC * 65; j += 256) ((float*)S_lds)[j] = 0.0f;
    if (tid < 64) rowbuf[tid >> 4][(tid >> 3) & 1][512 + (tid & 7)] = 0.0f;
    __syncthreads();

    // ---- histogram of this block's 512 labels ----
    const int* lp = label + b * NT + th * TQ + tid * 2;
    const int2 L = *(const int2*)lp;
    atomicAdd(&cnt[L.x], 1); atomicAdd(&cnt[L.y], 1);
    __syncthreads();

    // ---- prefix, classes padded to x4 (total <= 704 -> <=176 groups) ----
    if (tid == 0) {
        int pt = 0;
        for (int c = 0; c < NC; ++c) {
            int pl = (cnt[c] + 3) & ~3;
            pstart[c] = pt; pt += pl;
        }
    }
    __syncthreads();

    // group -> class map; groups beyond padded total stay class 0 (gather zeros)
    if (tid < NC) {
        int g0 = pstart[tid] >> 2;
        int g1 = g0 + (((cnt[tid] + 3) & ~3) >> 2);
        for (int g = g0; g < g1; ++g) gclass[g] = (unsigned char)tid;
    }
    // scatter: sorted[pos] = within-row byte offset of t
    {
        int p = pstart[L.x] + atomicAdd(&cursor[L.x], 1);
        sorted[p] = (unsigned short)((tid * 2 + 0) * 4);
        p = pstart[L.y] + atomicAdd(&cursor[L.y], 1);
        sorted[p] = (unsigned short)((tid * 2 + 1) * 4);
    }
    __syncthreads();

    // ---- lane-level groups: lane owns groups {lane, 64+lane, 128+lane} ----
    int offs[3][4]; int cls[3];
    #pragma unroll
    for (int g3 = 0; g3 < 3; ++g3) {
        const int g = lane + 64 * g3;
        const uint2 pk = *(const uint2*)&sorted[g * 4];
        offs[g3][0] = pk.x & 0xFFFF; offs[g3][1] = pk.x >> 16;
        offs[g3][2] = pk.y & 0xFFFF; offs[g3][3] = pk.y >> 16;
        cls[g3] = gclass[g];
    }

    // ---- hot loop: wave w rows w+4i, reg-staged, 2-deep pipeline ----
    // Lane l holds floats {4l..4l+3} and {256+4l..259+4l} of its row in two
    // float4s; ds_write_b128 x2 stages the row, then the sorted gather reads
    // it. Loads for row i+2 are issued right after row i's regs are consumed
    // by the ds_write -> ~2 iterations of HBM-latency hiding per wave, and
    // 16 waves/CU of TLP on the normal (non-DMA) global-load path.
    const float* fbase = feat + ((size_t)b * 128 + dh * 64) * NT + th * TQ;
    float ssA = 0.0f, ssB = 0.0f;

    float4 a0, b0, a1, b1;
    {
        const float* rp0 = fbase + (size_t)w * NT;
        const float* rp1 = fbase + (size_t)(w + 4) * NT;
        a0 = *(const float4*)(rp0 + lane * 4);
        b0 = *(const float4*)(rp0 + 256 + lane * 4);
        a1 = *(const float4*)(rp1 + lane * 4);
        b1 = *(const float4*)(rp1 + 256 + lane * 4);
    }

    #pragma unroll
    for (int i = 0; i < 16; ++i) {
        const int sl = i & 1;
        float* dst = &rowbuf[w][sl][0];
        if (sl == 0) {
            *(float4*)(dst + lane * 4)       = a0;   // vmcnt wait auto-inserted here
            *(float4*)(dst + 256 + lane * 4) = b0;
            if (i + 2 < 16) {
                const float* rp = fbase + (size_t)(w + 4 * (i + 2)) * NT;
                a0 = *(const float4*)(rp + lane * 4);
                b0 = *(const float4*)(rp + 256 + lane * 4);
            }
        } else {
            *(float4*)(dst + lane * 4)       = a1;
            *(float4*)(dst + 256 + lane * 4) = b1;
            if (i + 2 < 16) {
                const float* rp = fbase + (size_t)(w + 4 * (i + 2)) * NT;
                a1 = *(const float4*)(rp + lane * 4);
                b1 = *(const float4*)(rp + 256 + lane * 4);
            }
        }
        // gather (compiler inserts lgkmcnt ordering the ds_writes above
        // against these aliasing ds_reads; same-wave DS ops are in-order)
        const char* rb = (const char*)dst;
        const int dslot = w + 4 * i;         // d-index this wave accumulates (disjoint per wave)
        #pragma unroll
        for (int g3 = 0; g3 < 3; ++g3) {
            float v0 = *(const float*)(rb + offs[g3][0]);
            float v1 = *(const float*)(rb + offs[g3][1]);
            float v2 = *(const float*)(rb + offs[g3][2]);
            float v3 = *(const float*)(rb + offs[g3][3]);
            ssA += v0 * v0 + v1 * v1;
            ssB += v2 * v2 + v3 * v3;
            atomicAdd(&S_lds[cls[g3]][dslot], (v0 + v1) + (v2 + v3));
        }
    }

    // ---- global counts (one label-slice per (b,th); gate on dh==0) ----
    if (dh == 0 && tid < NC) atomicAdd((int*)(ws + OFF_CNT) + tid, cnt[tid]);

    __syncthreads();         // drains outstanding ds_add_f32; S_lds complete
    if (PARTIAL) {
        // non-atomic flush: block-contiguous 4096 floats, fully coalesced
        const int c = tid >> 2, j0 = (tid & 3) * 16;
        float* gP = ws + OFF_P + (size_t)bid * 4096 + c * 64 + j0;
        float4 v0, v1, v2, v3;
        v0.x = S_lds[c][j0 +  0]; v0.y = S_lds[c][j0 +  1];
        v0.z = S_lds[c][j0 +  2]; v0.w = S_lds[c][j0 +  3];
        v1.x = S_lds[c][j0 +  4]; v1.y = S_lds[c][j0 +  5];
        v1.z = S_lds[c][j0 +  6]; v1.w = S_lds[c][j0 +  7];
        v2.x = S_lds[c][j0 +  8]; v2.y = S_lds[c][j0 +  9];
        v2.z = S_lds[c][j0 + 10]; v2.w = S_lds[c][j0 + 11];
        v3.x = S_lds[c][j0 + 12]; v3.y = S_lds[c][j0 + 13];
        v3.z = S_lds[c][j0 + 14]; v3.w = S_lds[c][j0 + 15];
        *(float4*)gP        = v0;
        *(float4*)(gP + 4)  = v1;
        *(float4*)(gP + 8)  = v2;
        *(float4*)(gP + 12) = v3;
    } else {
        // fallback: global atomic flush (R8 path; correct, slow)
        const int c = tid >> 2, j0 = (tid & 3) * 16;
        float* gS = ws + OFF_S + (size_t)c * 128 + dh * 64 + j0;
        #pragma unroll
        for (int j = 0; j < 16; ++j) atomicAdd(&gS[j], S_lds[c][j0 + j]);
    }

    // ---- block sumsq reduce ----
    red[tid] = ssA + ssB;
    __syncthreads();
    for (int s = 128; s > 0; s >>= 1) {
        if (tid < s) red[tid] += red[tid + s];
        __syncthreads();
    }
    if (tid == 0) ws[OFF_SSP + bid] = red[0];
}

// main-path reduction: each block owns 32 (c,d) elements; 8 slices sum 64
// partial-blocks each (512 contributors per element = 128 b x 4 th).
__global__ __launch_bounds__(256) void k_red_p(float* __restrict__ ws,
                                               const float* __restrict__ centers,
                                               float* __restrict__ out) {
    const int tid = threadIdx.x, bid = blockIdx.x;
    const int j = tid & 31, s = tid >> 5;
    const int e = bid * 32 + j;
    const int c = e >> 7, d = e & 127, dhh = d >> 6, dl = d & 63;

    const float* base = ws + OFF_P + ((size_t)dhh * 4) * 4096 + c * 64 + dl;
    float sum = 0.0f;
    for (int b = s * 16; b < s * 16 + 16; ++b) {
        const float* pb = base + (size_t)b * 8 * 4096;
        sum += (pb[0] + pb[4096]) + (pb[2 * 4096] + pb[3 * 4096]);
    }

    __shared__ float red[256];
    red[tid] = sum;
    __syncthreads();
    if (tid < 128) red[tid] += red[tid + 128];
    __syncthreads();
    if (tid < 64)  red[tid] += red[tid + 64];
    __syncthreads();

    if (tid < 32) {
        const float tot = red[tid] + red[tid + 32];
        const float cn  = (float)((const int*)(ws + OFF_CNT))[c];
        const float ctr = centers[e];
        const float den = cn > 1.0f ? cn : 1.0f;
        out[1 + e] = (cn * ctr - tot) / den;

        float r1 = tot * ctr;          // cross term
        float r2 = cn * ctr * ctr;     // center-norm term
        for (int o = 16; o > 0; o >>= 1) {
            r1 += __shfl_down(r1, o, 32);
            r2 += __shfl_down(r2, o, 32);
        }
        if (tid == 0) { ws[OFF_CROSS + bid] = r1; ws[OFF_CC + bid] = r2; }
    }
}

// fallback reduction over the atomic S (R8 path)
__global__ __launch_bounds__(256) void k_red_a(float* __restrict__ ws,
                                               const float* __restrict__ centers,
                                               float* __restrict__ out) {
    const int tid = threadIdx.x, bid = blockIdx.x;
    const int e = bid * 256 + tid, c = e >> 7;
    const float sum = ws[OFF_S + e];
    const float cn  = (float)((const int*)(ws + OFF_CNT))[c];
    const float ctr = centers[e];
    const float den = cn > 1.0f ? cn : 1.0f;
    out[1 + e] = (cn * ctr - sum) / den;

    __shared__ float r1[256], r2[256];
    r1[tid] = sum * ctr;
    r2[tid] = cn * ctr * ctr;
    __syncthreads();
    for (int k = 128; k > 0; k >>= 1) {
        if (tid < k) { r1[tid] += r1[tid + k]; r2[tid] += r2[tid + k]; }
        __syncthreads();
    }
    if (tid == 0) { ws[OFF_CROSS + bid] = r1[0]; ws[OFF_CC + bid] = r2[0]; }
}

__global__ __launch_bounds__(256) void k_epi(const float* __restrict__ ws,
                                             float* __restrict__ out,
                                             int ncross) {
    const int tid = threadIdx.x;
    __shared__ float r[256];
    float s = ws[OFF_SSP + tid] + ws[OFF_SSP + tid + 256]
            + ws[OFF_SSP + tid + 512] + ws[OFF_SSP + tid + 768];
    if (tid < ncross) s += ws[OFF_CC + tid] - 2.0f * ws[OFF_CROSS + tid];
    r[tid] = s;
    __syncthreads();
    for (int k = 128; k > 0; k >>= 1) {
        if (tid < k) r[tid] += r[tid + k];
        __syncthreads();
    }
    if (tid == 0) out[0] = r[0] * (1.0f / 33554432.0f);  // / (N*D), N = B*T
}

extern "C" void kernel_launch(void* const* d_in, const int* in_sizes, int n_in,
                              void* d_out, int out_size, void* d_ws, size_t ws_size,
                              hipStream_t stream) {
    const float* feat    = (const float*)d_in[0];
    const int*   label   = (const int*)d_in[1];
    const float* centers = (const float*)d_in[2];
    float* out = (float*)d_out;
    float* ws  = (float*)d_ws;

    // zero atomic accumulators (S fallback + CNT); capture-safe stream op
    hipMemsetAsync(ws, 0, 8256 * sizeof(float), stream);

    if (ws_size >= WS_NEED_BYTES) {
        hipLaunchKernelGGL(k_main<true>,  dim3(1024), dim3(256), 0, stream, feat, label, ws);
        hipLaunchKernelGGL(k_red_p, dim3(256), dim3(256), 0, stream, ws, centers, out);
        hipLaunchKernelGGL(k_epi,   dim3(1),   dim3(256), 0, stream, ws, out, 256);
    } else {
        hipLaunchKernelGGL(k_main<false>, dim3(1024), dim3(256), 0, stream, feat, label, ws);
        hipLaunchKernelGGL(k_red_a, dim3(32),  dim3(256), 0, stream, ws, centers, out);
        hipLaunchKernelGGL(k_epi,   dim3(1),   dim3(256), 0, stream, ws, out, 32);
    }
}